// Round 3
// baseline (101.741 us; speedup 1.0000x reference)
//
#include <hip/hip_runtime.h>

#define BB 4
#define CC 3
#define HH 512
#define WW 512
#define NS 81              // 9 x 9 shifts
#define IMG (HH * WW)
#define CHW (CC * IMG)
#define STRIP 8            // rows per k_sims block
#define NSTRIPS (HH / STRIP)             // 64
#define NBLK (BB * CC * NSTRIPS)         // 768 blocks = exactly 3/CU
#define SLOTS (CC * NSTRIPS)             // 192 partials per (b, sim)

// R14: R13's all-sx-per-block structure (the 16 us win) + three latency levers:
//  - STRIP 8 -> 768 blocks: perfect 3-blocks/CU balance, 27 waves/CU TLP
//    (R13: 384 blocks = 1.5/CU -> serialized tail + 3.4 waves/SIMD)
//  - __launch_bounds__(576,4): cap VGPR<=128 so >=2 blocks co-reside
//  - halo via direct loads (R12's exact body): kills the VMEM->ds_permute->
//    FMA serial chain; halo rows are L1-hits now that 9 waves share the CU
__device__ double g_part[(size_t)BB * NS * SLOTS];   // 497 KB, fully rewritten each launch
__device__ int    g_best[BB];

// constant-index component select (folds after full unroll)
#define C4(v, i) ((i) == 0 ? (v).x : (i) == 1 ? (v).y : (i) == 2 ? (v).z : (v).w)

// sim(b,sx,sy) = sum over c,i,j (both (i,j) and (i+sx,j+sy) in bounds) of
//               x[b,c,i,j] * x_ref[b,c,i+sx,j+sy]
__global__ __launch_bounds__(576, 4) void k_sims(const float* __restrict__ xref,
                                                 const float* __restrict__ x) {
    // XCD-contiguous swizzle (bijective: 768 % 8 == 0). Adjacent strips share
    // 8 halo rows -> keep them on the same XCD's L2.
    int raw   = blockIdx.x;
    int bid   = (raw & 7) * (NBLK / 8) + (raw >> 3);
    int strip = bid % NSTRIPS;
    int bc    = bid / NSTRIPS;
    int b     = bc / CC;
    const float* xp = x    + (size_t)bc * IMG;
    const float* rp = xref + (size_t)bc * IMG;
    int tid  = threadIdx.x;
    int lane = tid & 63;
    int sxi  = tid >> 6;                 // wave index == sx index (9 waves)
    int j0   = lane << 3;                // 8 floats per lane
    int sx   = sxi - 4;
    int ip0  = strip * STRIP;

    float acc[9];
#pragma unroll
    for (int s = 0; s < 9; ++s) acc[s] = 0.f;

#pragma unroll
    for (int rr = 0; rr < STRIP; ++rr) {
        int ip = ip0 + rr;               // x row (always in bounds)
        int ii = ip + sx;                // ref row (wave-uniform test)
        if ((unsigned)ii >= HH) continue;

        const float* xrow = xp + ip * WW + j0;
        const float* rrow = rp + ii * WW + j0;
        float4 xa = *(const float4*)(xrow);        // x   cols j0   .. j0+3
        float4 xb = *(const float4*)(xrow + 4);    // x   cols j0+4 .. j0+7

        // ref window cols j0-4 .. j0+11: four 16B-aligned dwordx4 loads
        // (all L1-hits except first toucher). Lane 0/63 redirect in-row
        // (never OOB) then zero-select the halo. Exactness proven in R12.
        const float4* pp = (const float4*)(rrow + (lane == 0  ? 0 : -4));
        const float4* np = (const float4*)(rrow + (lane == 63 ? 0 :  8));
        float4 pv = *pp;                           // ref cols j0-4 .. j0-1
        float4 ra = *(const float4*)(rrow);        // ref cols j0   .. j0+3
        float4 rb = *(const float4*)(rrow + 4);    // ref cols j0+4 .. j0+7
        float4 nv = *np;                           // ref cols j0+8 .. j0+11
        if (lane == 0)  pv = make_float4(0.f, 0.f, 0.f, 0.f);  // cols < 0
        if (lane == 63) nv = make_float4(0.f, 0.f, 0.f, 0.f);  // cols >= 512

#pragma unroll
        for (int syi = 0; syi < 9; ++syi) {
#pragma unroll
            for (int k = 0; k < 8; ++k) {
                int i = k + syi;         // window index 0..15 (constant)
                float wv = (i < 4)  ? C4(pv, i)
                         : (i < 8)  ? C4(ra, i - 4)
                         : (i < 12) ? C4(rb, i - 8)
                         :            C4(nv, i - 12);
                float xv = (k < 4) ? C4(xa, k) : C4(xb, k - 4);
                acc[syi] += xv * wv;
            }
        }
    }

    // Each wave owns 9 disjoint sims (its sx) -> no LDS combine, no atomics.
    // Wave shuffle-reduce (fp32), lane 0 stores fp64 partial.
    // Numerics: fp32 chunk is 8 rows (same as R11), fixed combine order.
    int cs = (bc % CC) * NSTRIPS + strip;            // partial slot 0..191
#pragma unroll
    for (int s = 0; s < 9; ++s) {
        float v = acc[s];
        for (int off = 32; off; off >>= 1) v += __shfl_down(v, off, 64);
        if (lane == 0)
            g_part[((size_t)b * NS + sxi * 9 + s) * SLOTS + cs] = (double)v;
    }
}

// Tiny reduce: one block per batch; thread t sums its sim's 192 consecutive
// fp64 partials (fixed even/odd 2-way order -> deterministic), then
// first-index argmax (matches jnp.argmax), writes g_best + shift tail.
__global__ __launch_bounds__(128) void k_reduce(float* __restrict__ outTail) {
    int b = blockIdx.x;
    int t = threadIdx.x;
    __shared__ double vals[NS];
    if (t < NS) {
        const double* p = g_part + ((size_t)b * NS + t) * SLOTS;
        double s0 = 0.0, s1 = 0.0;
        for (int i = 0; i < SLOTS; i += 2) { s0 += p[i]; s1 += p[i + 1]; }
        vals[t] = s0 + s1;
    }
    __syncthreads();
    if (t == 0) {
        int best = 0;
        double bv = vals[0];
        for (int i = 1; i < NS; ++i)
            if (vals[i] > bv) { bv = vals[i]; best = i; }   // strict >: first index wins
        g_best[b] = best;
        outTail[b * 2]     = (float)(best / 9 - 4);
        outTail[b * 2 + 1] = (float)(best % 9 - 4);
    }
}

// Pure shift-copy: reads precomputed g_best[b] (wave-uniform scalar load).
// Copy body unchanged from R11/R12/R13 (proven exact).
__global__ __launch_bounds__(256) void k_apply(const float* __restrict__ x,
                                               float* __restrict__ out) {
    int blk = blockIdx.x;
    int bc  = blk >> 8;                 // 256 blocks per image (512 rows / 2)
    int tid = threadIdx.x;
    int b   = bc / CC;

    int bi = g_best[b];
    int sx = bi / 9 - 4;
    int sy = bi % 9 - 4;

    int row = ((blk & 255) << 1) + (tid >> 7);
    int j0  = (tid & 127) << 2;
    int is  = row - sx;
    float4 v = make_float4(0.f, 0.f, 0.f, 0.f);
    if ((unsigned)is < HH) {
        const float* src = x + (size_t)bc * IMG + is * WW;
        int js0 = j0 - sy;
        if (js0 >= 0 && js0 + 3 < WW) {
            v = *(const float4*)(src + js0);   // 4B-aligned dwordx4, exact (R2-R14)
        } else {
            float* vv = (float*)&v;
#pragma unroll
            for (int k = 0; k < 4; ++k) {
                int js = js0 + k;
                if ((unsigned)js < WW) vv[k] = src[js];
            }
        }
    }
    *(float4*)(out + (size_t)bc * IMG + row * WW + j0) = v;
}

extern "C" void kernel_launch(void* const* d_in, const int* in_sizes, int n_in,
                              void* d_out, int out_size, void* d_ws, size_t ws_size,
                              hipStream_t stream) {
    const float* xref = (const float*)d_in[0];
    const float* x    = (const float*)d_in[1];
    float* out = (float*)d_out;
    (void)d_ws; (void)ws_size;          // workspace unused (poison fill is unconditional)

    k_sims<<<NBLK, 576, 0, stream>>>(xref, x);
    k_reduce<<<BB, 128, 0, stream>>>(out + (size_t)BB * CHW);

    int applyBlocks = (BB * CC * HH) / 2;   // 3072
    k_apply<<<applyBlocks, 256, 0, stream>>>(x, out);
}